// Round 4
// baseline (175.993 us; speedup 1.0000x reference)
//
#include <hip/hip_runtime.h>

#define B_DIM   4096
#define IN_DIM  512
#define OUT_DIM 512
#define KTOT    18432              // IN*36
#define BK      64
#define KSPLIT  8
#define KPER    2304               // KTOT/KSPLIT = 64 i-blocks (aligned)
#define NT      36                 // K-tiles per block

using f32x4 = __attribute__((ext_vector_type(4))) float;
using s16x8 = __attribute__((ext_vector_type(8))) short;
using u32x4 = __attribute__((ext_vector_type(4))) unsigned int;

__device__ __forceinline__ unsigned int f2bf(float f) {
    unsigned int u = __float_as_uint(f);
    return (u + 0x7FFFu + ((u >> 16) & 1u)) >> 16;
}

__device__ __forceinline__ void glds16(const void* g, void* l) {
    __builtin_amdgcn_global_load_lds(
        (const __attribute__((address_space(1))) unsigned int*)g,
        (__attribute__((address_space(3))) unsigned int*)l,
        16, 0, 0);
}

// Exact np.linspace(-1,1,10) + searchsorted(knots[1:], 'left') + clip, in f64.
__device__ __forceinline__ uint2 spline_rec_packed(float xv) {
    float xc = fminf(fmaxf(xv, -1.0f), 1.0f);
    double xd = (double)xc;
    int s = 0;
#pragma unroll
    for (int k = 1; k <= 8; ++k)
        s += ((-1.0 + (double)k * (2.0 / 9.0)) < xd) ? 1 : 0;
    double lo = -1.0 + (double)s * (2.0 / 9.0);
    double hi = -1.0 + (double)(s + 1) * (2.0 / 9.0);
    float t  = (float)((xd - lo) / (hi - lo));
    float t2 = t * t, t3 = t2 * t;
    uint2 r;
    r.x = f2bf(t)  | (f2bf(t2) << 16);
    r.y = f2bf(t3) | ((unsigned int)s << 16);
    return r;
}

// Prepass 1: per (b,i) packed tpow+seg record (8B), layout [B][IN]
__global__ void prep_x_kernel(const float* __restrict__ x, uint2* __restrict__ tp) {
    int idx = blockIdx.x * 256 + threadIdx.x;
    if (idx >= B_DIM * IN_DIM) return;
    tp[idx] = spline_rec_packed(x[idx]);
}

// Prepass 2: coeff -> bf16 (scale folded), 128-wide N-tile image:
// [nt(4)][kt(288)][oct(8)][row(128)][8 bf16] so glds-linear == LDS image.
__global__ void prep_coeff2(const float* __restrict__ c,
                            const float* __restrict__ scale,
                            u32x4* __restrict__ cbf2) {
    int g = blockIdx.x * 256 + threadIdx.x;        // one per 16B granule
    if (g >= (OUT_DIM * KTOT) / 8) return;
    int row = g & 127;
    int oct = (g >> 7) & 7;
    int hi  = g >> 10;                             // nt*288 + kt, 0..1151
    int ntg = hi / 288;
    int kt  = hi - ntg * 288;
    int j = ntg * 128 + row;
    int k = kt * 64 + oct * 8;
    float s = scale[j];
    const float* src = c + (size_t)j * KTOT + k;
    f32x4 a = *(const f32x4*)src;
    f32x4 b = *(const f32x4*)(src + 4);
    u32x4 o;
    o.x = f2bf(a.x * s) | (f2bf(a.y * s) << 16);
    o.y = f2bf(a.z * s) | (f2bf(a.w * s) << 16);
    o.z = f2bf(b.x * s) | (f2bf(b.y * s) << 16);
    o.w = f2bf(b.z * s) | (f2bf(b.w * s) << 16);
    cbf2[g] = o;
}

// scatter 3 candidate records into the staging A tile (own 32-elem half only)
__device__ __forceinline__ void scat3(char* Aq, int ar, int ah,
                                      uint2 q0, uint2 q1, uint2 q2,
                                      int ifirst, int k0) {
#pragma unroll
    for (int cc = 0; cc < 3; ++cc) {
        uint2 rec = cc == 0 ? q0 : (cc == 1 ? q1 : q2);
        int i = ifirst + cc;
        if (i < IN_DIM) {
            int s = (int)(rec.y >> 16);
            int off = i * 36 + s * 4 - k0;                 // multiple of 4
            if (off >= 0 && off < 64 && ((off >> 5) == ah)) {
                uint2 w;
                w.x = 0x3F80u | (rec.x << 16);             // {1, t}
                w.y = (rec.x >> 16) | (rec.y << 16);       // {t2, t3}
                *(uint2*)(Aq + (off >> 3) * 2048 + ar * 16 + (off & 4) * 2) = w;
            }
        }
    }
}

// 128x128 tile, 4 waves, BK=64, double-buffered LDS (64KB), ONE __syncthreads/step.
// T3-minimum recipe: STAGE(t+1) issued BEFORE compute(t); syncthreads drains all.
__launch_bounds__(256, 2)
__global__ void kan_gemm_db(const unsigned short* __restrict__ cbf2,
                            const uint2* __restrict__ tp,
                            float* __restrict__ out) {
    // [0,16K)=A0  [16K,32K)=A1  [32K,48K)=B0  [48K,64K)=B1
    // A/B tile: [8 oct][128 row][16B], entry (oct,row) = 8 bf16 of k0+oct*8..+8
    __shared__ u32x4 ldsRaw[65536 / 16];
    char* lds = (char*)ldsRaw;

    const int tid  = threadIdx.x;
    const int lane = tid & 63;
    const int wave = tid >> 6;
    const int wm = wave >> 1, wn = wave & 1;
    const int l15 = lane & 15, lhi = lane >> 4;

    const int bid = blockIdx.x;                    // grid 1024
    const int nt = bid & 3;
    const int ks = (bid >> 2) & 7;
    const int mt = bid >> 5;
    const int m0g = mt * 128, n0g = nt * 128;
    const int kbase = ks * KPER;

    const int ar = tid & 127, ah = tid >> 7;       // staging row / oct-half (wave-linear)

    const uint2* tpRow = tp + (size_t)(m0g + ar) * IN_DIM;
    const char*  cbase = (const char*)cbf2 + (size_t)(nt * 288 + ks * NT) * 16384;

    f32x4 acc[4][4] = {};
    uint2 r0, r1, r2;

    // ---------------- prologue: build tile 0 in buf0, prefetch recs(tile 1) ----------------
    {
        char* A0 = lds;
        char* B0 = lds + 32768;
        const int if0 = kbase / 36;
        uint2 q0 = tpRow[if0];
        uint2 q1 = tpRow[if0 + 1 < IN_DIM ? if0 + 1 : IN_DIM - 1];
        uint2 q2 = tpRow[if0 + 2 < IN_DIM ? if0 + 2 : IN_DIM - 1];
        u32x4 z = {};
#pragma unroll
        for (int zi = 0; zi < 4; ++zi)
            *(u32x4*)(A0 + (ah * 4 + zi) * 2048 + ar * 16) = z;
        scat3(A0, ar, ah, q0, q1, q2, if0, kbase);
#pragma unroll
        for (int it = 0; it < 4; ++it)
            glds16(cbase + it * 4096 + tid * 16, B0 + it * 4096 + tid * 16);
        const int if1 = (kbase + BK) / 36;
        r0 = tpRow[if1];
        r1 = tpRow[if1 + 1 < IN_DIM ? if1 + 1 : IN_DIM - 1];
        r2 = tpRow[if1 + 2 < IN_DIM ? if1 + 2 : IN_DIM - 1];
        __syncthreads();                            // full drain (vmcnt0+lgkm0) + barrier
    }

    for (int t = 0; t < NT; ++t) {
        const int p = t & 1;
        const char* Ap = lds + p * 16384;
        const char* Bp = lds + 32768 + p * 16384;
        char* Aq = lds + (p ^ 1) * 16384;
        char* Bq = lds + 32768 + (p ^ 1) * 16384;

        // ---- STAGE tile t+1 (issued before compute so latency hides under MFMA) ----
        if (t + 1 < NT) {
            const int k0n = kbase + (t + 1) * BK;
            u32x4 z = {};
#pragma unroll
            for (int zi = 0; zi < 4; ++zi)
                *(u32x4*)(Aq + (ah * 4 + zi) * 2048 + ar * 16) = z;
            scat3(Aq, ar, ah, r0, r1, r2, k0n / 36, k0n);
            const char* srcT = cbase + (size_t)(t + 1) * 16384;
#pragma unroll
            for (int it = 0; it < 4; ++it)
                glds16(srcT + it * 4096 + tid * 16, Bq + it * 4096 + tid * 16);
            // prefetch recs for tile t+2 (consumed next iteration)
            const int tn = t + 2 < NT ? t + 2 : NT - 1;
            const int ifn = (kbase + tn * BK) / 36;
            r0 = tpRow[ifn];
            r1 = tpRow[ifn + 1 < IN_DIM ? ifn + 1 : IN_DIM - 1];
            r2 = tpRow[ifn + 2 < IN_DIM ? ifn + 2 : IN_DIM - 1];
        }

        // ---- COMPUTE tile t ----
#pragma unroll
        for (int kh = 0; kh < 2; ++kh) {
            s16x8 a[4], b[4];
#pragma unroll
            for (int mf = 0; mf < 4; ++mf)
                a[mf] = *(const s16x8*)(Ap + (kh * 4 + lhi) * 2048 + (wm * 64 + mf * 16 + l15) * 16);
#pragma unroll
            for (int nf = 0; nf < 4; ++nf)
                b[nf] = *(const s16x8*)(Bp + (kh * 4 + lhi) * 2048 + (wn * 64 + nf * 16 + l15) * 16);
#pragma unroll
            for (int mf = 0; mf < 4; ++mf)
#pragma unroll
                for (int nf = 0; nf < 4; ++nf)
                    acc[mf][nf] = __builtin_amdgcn_mfma_f32_16x16x32_bf16(a[mf], b[nf], acc[mf][nf], 0, 0, 0);
        }

        __syncthreads();   // drains my ds_writes + glds (vmcnt0) + my ds_reads; then barrier
    }

    // ---- epilogue: split-K accumulate. C/D: col=lane&15 (n), row=(lane>>4)*4+e (m) ----
#pragma unroll
    for (int mf = 0; mf < 4; ++mf) {
        const int rg = m0g + wm * 64 + mf * 16 + lhi * 4;
#pragma unroll
        for (int nf = 0; nf < 4; ++nf) {
            const int cg = n0g + wn * 64 + nf * 16 + l15;
#pragma unroll
            for (int e = 0; e < 4; ++e)
                atomicAdd(out + (size_t)(rg + e) * OUT_DIM + cg, acc[mf][nf][e]);
        }
    }
}

// ---------------- fallback (no workspace): round-1 proven kernel ----------------
#define BM 128
#define BN 128
#define FKPER  4608
#define FSTEPS 72
__launch_bounds__(256, 2)
__global__ void kan_gemm_ref(const float* __restrict__ x,
                             const float* __restrict__ coeff,
                             const float* __restrict__ scale,
                             float* __restrict__ out) {
    __shared__ unsigned short AsF[BM * 72];
    __shared__ unsigned short BsF[8 * BN * 8];
    const int tid  = threadIdx.x;
    const int lane = tid & 63;
    const int wave = tid >> 6;
    const int wm = wave >> 1, wn = wave & 1;
    const int l15 = lane & 15, lhi = lane >> 4;
    const int bid = blockIdx.x;
    const int nt = bid & 3;
    const int ks = (bid >> 2) & 3;
    const int mt = bid >> 4;
    const int m0g = mt * BM, n0g = nt * BN, kbase = ks * FKPER;
    const int ar = tid >> 1, ah = tid & 1;
    const int abrow = m0g + ar;
    const int bjg = n0g + (tid & 127);
    const float bscale = scale[bjg];
    char* AsB = (char*)AsF;
    char* BsB = (char*)BsF;
    f32x4 acc[4][4] = {};
    for (int step = 0; step < FSTEPS; ++step) {
        const int k0 = kbase + step * BK;
        {
            char* rb = AsB + ar * 144;
            u32x4 z = {};
            if (ah == 0) {
#pragma unroll
                for (int z4 = 0; z4 < 4; ++z4) *(u32x4*)(rb + z4 * 16) = z;
            } else {
#pragma unroll
                for (int z4 = 4; z4 < 9; ++z4) *(u32x4*)(rb + z4 * 16) = z;
            }
            const int ifirst = k0 / 36;
#pragma unroll
            for (int ii = 0; ii < 2; ++ii) {
                const int cand = ah + ii * 2;
                const int i = ifirst + cand;
                if (cand < 3 && i * 36 < k0 + BK && i < IN_DIM) {
                    uint2 rec = spline_rec_packed(x[(size_t)abrow * IN_DIM + i]);
                    int s = (int)(rec.y >> 16);
                    const int off = i * 36 + s * 4 - k0;
                    unsigned int w0 = 0x3F80u | (rec.x << 16);
                    unsigned int w1 = (rec.x >> 16) | (rec.y << 16);
                    if (off >= 0 && off <= 62) *(unsigned int*)(rb + off * 2) = w0;
                    const int off2 = off + 2;
                    if (off2 >= 0 && off2 <= 62) *(unsigned int*)(rb + off2 * 2) = w1;
                }
            }
        }
#pragma unroll
        for (int it = 0; it < 4; ++it) {
            const int q  = it * 256 + tid;
            const int c  = q >> 7;
            const int kk = k0 + c * 8;
            f32x4 a = *(const f32x4*)(coeff + (size_t)bjg * KTOT + kk);
            f32x4 b = *(const f32x4*)(coeff + (size_t)bjg * KTOT + kk + 4);
            u32x4 o;
            o.x = f2bf(a.x * bscale) | (f2bf(a.y * bscale) << 16);
            o.y = f2bf(a.z * bscale) | (f2bf(a.w * bscale) << 16);
            o.z = f2bf(b.x * bscale) | (f2bf(b.y * bscale) << 16);
            o.w = f2bf(b.z * bscale) | (f2bf(b.w * bscale) << 16);
            *(u32x4*)(BsB + q * 16) = o;
        }
        __syncthreads();
#pragma unroll
        for (int kh = 0; kh < 2; ++kh) {
            const int kk = kh * 32;
            s16x8 a[4], b[4];
#pragma unroll
            for (int mf = 0; mf < 4; ++mf)
                a[mf] = *(const s16x8*)(AsB + (wm * 64 + mf * 16 + l15) * 144 + (kk + lhi * 8) * 2);
#pragma unroll
            for (int nf = 0; nf < 4; ++nf)
                b[nf] = *(const s16x8*)(BsB + (kh * 4 + lhi) * 2048 + (wn * 64 + nf * 16 + l15) * 16);
#pragma unroll
            for (int mf = 0; mf < 4; ++mf)
#pragma unroll
                for (int nf = 0; nf < 4; ++nf)
                    acc[mf][nf] = __builtin_amdgcn_mfma_f32_16x16x32_bf16(a[mf], b[nf], acc[mf][nf], 0, 0, 0);
        }
        __syncthreads();
    }
#pragma unroll
    for (int mf = 0; mf < 4; ++mf) {
        const int cmBase = m0g + wm * 64 + mf * 16 + lhi * 4;
#pragma unroll
        for (int nf = 0; nf < 4; ++nf) {
            const int cn = n0g + wn * 64 + nf * 16 + l15;
#pragma unroll
            for (int e = 0; e < 4; ++e)
                atomicAdd(out + (size_t)(cmBase + e) * OUT_DIM + cn, acc[mf][nf][e]);
        }
    }
}

extern "C" void kernel_launch(void* const* d_in, const int* in_sizes, int n_in,
                              void* d_out, int out_size, void* d_ws, size_t ws_size,
                              hipStream_t stream) {
    const float* x     = (const float*)d_in[0];
    const float* coeff = (const float*)d_in[1];
    const float* scale = (const float*)d_in[2];
    float* out = (float*)d_out;

    const size_t SZ_CBF = (size_t)OUT_DIM * KTOT * 2;   // 18,874,368
    const size_t SZ_TP  = (size_t)B_DIM * IN_DIM * 8;   // 16,777,216
    const size_t NEED   = SZ_CBF + SZ_TP;               // ~35.7 MB

    hipMemsetAsync(d_out, 0, (size_t)B_DIM * OUT_DIM * sizeof(float), stream);

    if (ws_size >= NEED) {
        unsigned short* cbf2 = (unsigned short*)d_ws;
        uint2*          tp   = (uint2*)((char*)d_ws + SZ_CBF);
        prep_coeff2<<<4608, 256, 0, stream>>>(coeff, scale, (u32x4*)cbf2);
        prep_x_kernel<<<8192, 256, 0, stream>>>(x, tp);
        kan_gemm_db<<<1024, 256, 0, stream>>>(cbf2, tp, out);
    } else {
        kan_gemm_ref<<<512, 256, 0, stream>>>(x, coeff, scale, out);
    }
}

// Round 5
// 163.970 us; speedup vs baseline: 1.0733x; 1.0733x over previous
//
#include <hip/hip_runtime.h>

#define B_DIM   4096
#define IN_DIM  512
#define OUT_DIM 512
#define KTOT    18432              // IN*36
#define BK      32
#define KSPLIT  8
#define KPER    2304               // KTOT/KSPLIT = 64 i-blocks (aligned)
#define NT      72                 // K-tiles per block (KPER/BK)

using f32x4 = __attribute__((ext_vector_type(4))) float;
using s16x8 = __attribute__((ext_vector_type(8))) short;
using u32x4 = __attribute__((ext_vector_type(4))) unsigned int;

__device__ __forceinline__ unsigned int f2bf(float f) {
    unsigned int u = __float_as_uint(f);
    return (u + 0x7FFFu + ((u >> 16) & 1u)) >> 16;
}

__device__ __forceinline__ void glds16(const void* g, void* l) {
    __builtin_amdgcn_global_load_lds(
        (const __attribute__((address_space(1))) unsigned int*)g,
        (__attribute__((address_space(3))) unsigned int*)l,
        16, 0, 0);
}

// Exact np.linspace(-1,1,10) + searchsorted(knots[1:], 'left') + clip, in f64.
__device__ __forceinline__ uint2 spline_rec_packed(float xv) {
    float xc = fminf(fmaxf(xv, -1.0f), 1.0f);
    double xd = (double)xc;
    int s = 0;
#pragma unroll
    for (int k = 1; k <= 8; ++k)
        s += ((-1.0 + (double)k * (2.0 / 9.0)) < xd) ? 1 : 0;
    double lo = -1.0 + (double)s * (2.0 / 9.0);
    double hi = -1.0 + (double)(s + 1) * (2.0 / 9.0);
    float t  = (float)((xd - lo) / (hi - lo));
    float t2 = t * t, t3 = t2 * t;
    uint2 r;
    r.x = f2bf(t)  | (f2bf(t2) << 16);
    r.y = f2bf(t3) | ((unsigned int)s << 16);
    return r;
}

// Prepass 1: per (b,i) packed tpow+seg record (8B), layout [B][IN]
__global__ void prep_x_kernel(const float* __restrict__ x, uint2* __restrict__ tp) {
    int idx = blockIdx.x * 256 + threadIdx.x;
    if (idx >= B_DIM * IN_DIM) return;
    tp[idx] = spline_rec_packed(x[idx]);
}

// Prepass 2: coeff -> bf16 (scale folded), BK=32 tile image:
// [nt(4)][kt(576)][oct(4)][row(128)][8 bf16] so glds-linear == LDS image.
__global__ void prep_coeff2(const float* __restrict__ c,
                            const float* __restrict__ scale,
                            u32x4* __restrict__ cbf2) {
    int g = blockIdx.x * 256 + threadIdx.x;        // one per 16B granule
    if (g >= (OUT_DIM * KTOT) / 8) return;
    int row = g & 127;
    int oct = (g >> 7) & 3;
    int hi  = g >> 9;                              // nt*576 + kt, 0..2303
    int ntg = hi / 576;
    int kt  = hi - ntg * 576;
    int j = ntg * 128 + row;
    int k = kt * 32 + oct * 8;
    float s = scale[j];
    const float* src = c + (size_t)j * KTOT + k;
    f32x4 a = *(const f32x4*)src;
    f32x4 b = *(const f32x4*)(src + 4);
    u32x4 o;
    o.x = f2bf(a.x * s) | (f2bf(a.y * s) << 16);
    o.y = f2bf(a.z * s) | (f2bf(a.w * s) << 16);
    o.z = f2bf(b.x * s) | (f2bf(b.y * s) << 16);
    o.w = f2bf(b.z * s) | (f2bf(b.w * s) << 16);
    cbf2[g] = o;
}

// scatter up to 2 candidate records into the staging A tile (own 2 octets only)
__device__ __forceinline__ void scat2(char* Aq, int ar, int ah,
                                      uint2 q0, uint2 q1, int ifirst, int k0) {
#pragma unroll
    for (int cc = 0; cc < 2; ++cc) {
        uint2 rec = cc == 0 ? q0 : q1;
        int i = ifirst + cc;
        if (i < IN_DIM) {
            int s = (int)(rec.y >> 16);
            int off = i * 36 + s * 4 - k0;                 // multiple of 4; never straddles
            if (off >= 0 && off < BK && ((off >> 4) == ah)) {
                uint2 w;
                w.x = 0x3F80u | (rec.x << 16);             // {1, t}
                w.y = (rec.x >> 16) | (rec.y << 16);       // {t2, t3}
                *(uint2*)(Aq + (off >> 3) * 2048 + ar * 16 + (off & 4) * 2) = w;
            }
        }
    }
}

// 128x128 tile, 4 waves, BK=32, double-buffered LDS (32KB -> 4 blocks/CU),
// ONE __syncthreads/step. STAGE(t+1) issued before compute(t).
__launch_bounds__(256, 4)
__global__ void kan_gemm_db(const unsigned short* __restrict__ cbf2,
                            const uint2* __restrict__ tp,
                            float* __restrict__ out) {
    // [0,8K)=A0 [8K,16K)=A1 [16K,24K)=B0 [24K,32K)=B1
    // A/B tile: [4 oct][128 row][16B], entry (oct,row) = 8 bf16 of k0+oct*8..+8
    __shared__ u32x4 ldsRaw[32768 / 16];
    char* lds = (char*)ldsRaw;

    const int tid  = threadIdx.x;
    const int lane = tid & 63;
    const int wave = tid >> 6;
    const int wm = wave >> 1, wn = wave & 1;
    const int l15 = lane & 15, lhi = lane >> 4;

    const int bid = blockIdx.x;                    // grid 1024 = mt*32 + ks*4 + nt
    const int nt = bid & 3;
    const int ks = (bid >> 2) & 7;
    const int mt = bid >> 5;
    const int m0g = mt * 128, n0g = nt * 128;
    const int kbase = ks * KPER;

    const int ar = tid & 127, ah = tid >> 7;       // staging row / octet-pair owner

    const uint2* tpRow = tp + (size_t)(m0g + ar) * IN_DIM;
    const char*  cbase = (const char*)cbf2 + (size_t)(nt * 576 + ks * NT) * 8192;

    f32x4 acc[4][4] = {};
    uint2 r0, r1;

    // ---------------- prologue: build tile 0 in buf0, prefetch recs(tile 1) ----------------
    {
        char* A0 = lds;
        char* B0 = lds + 16384;
#pragma unroll
        for (int it = 0; it < 2; ++it)
            glds16(cbase + it * 4096 + tid * 16, B0 + it * 4096 + tid * 16);
        const int if0 = kbase / 36;
        uint2 q0 = tpRow[if0];
        uint2 q1 = tpRow[if0 + 1 < IN_DIM ? if0 + 1 : IN_DIM - 1];
        u32x4 z = {};
#pragma unroll
        for (int zi = 0; zi < 2; ++zi)
            *(u32x4*)(A0 + (ah * 2 + zi) * 2048 + ar * 16) = z;
        scat2(A0, ar, ah, q0, q1, if0, kbase);
        const int if1 = (kbase + BK) / 36;
        r0 = tpRow[if1];
        r1 = tpRow[if1 + 1 < IN_DIM ? if1 + 1 : IN_DIM - 1];
        __syncthreads();                            // full drain (vmcnt0+lgkm0) + barrier
    }

    for (int t = 0; t < NT; ++t) {
        const int p = t & 1;
        const char* Ap = lds + p * 8192;
        const char* Bp = lds + 16384 + p * 8192;
        char* Aq = lds + (p ^ 1) * 8192;
        char* Bq = lds + 16384 + (p ^ 1) * 8192;

        // ---- STAGE tile t+1 (glds first: deepest latency; then A construct) ----
        if (t + 1 < NT) {
            const int k0n = kbase + (t + 1) * BK;
            const char* srcT = cbase + (size_t)(t + 1) * 8192;
#pragma unroll
            for (int it = 0; it < 2; ++it)
                glds16(srcT + it * 4096 + tid * 16, Bq + it * 4096 + tid * 16);
            u32x4 z = {};
#pragma unroll
            for (int zi = 0; zi < 2; ++zi)
                *(u32x4*)(Aq + (ah * 2 + zi) * 2048 + ar * 16) = z;
            scat2(Aq, ar, ah, r0, r1, k0n / 36, k0n);
            // prefetch recs for tile t+2 (consumed next iteration)
            const int tn = t + 2 < NT ? t + 2 : NT - 1;
            const int ifn = (kbase + tn * BK) / 36;
            r0 = tpRow[ifn];
            r1 = tpRow[ifn + 1 < IN_DIM ? ifn + 1 : IN_DIM - 1];
        }

        // ---- COMPUTE tile t: K=32 = exactly one MFMA per frag pair ----
        {
            s16x8 a[4], b[4];
#pragma unroll
            for (int mf = 0; mf < 4; ++mf)
                a[mf] = *(const s16x8*)(Ap + lhi * 2048 + (wm * 64 + mf * 16 + l15) * 16);
#pragma unroll
            for (int nf = 0; nf < 4; ++nf)
                b[nf] = *(const s16x8*)(Bp + lhi * 2048 + (wn * 64 + nf * 16 + l15) * 16);
#pragma unroll
            for (int mf = 0; mf < 4; ++mf)
#pragma unroll
                for (int nf = 0; nf < 4; ++nf)
                    acc[mf][nf] = __builtin_amdgcn_mfma_f32_16x16x32_bf16(a[mf], b[nf], acc[mf][nf], 0, 0, 0);
        }

        __syncthreads();   // drains my ds_writes + glds (vmcnt0) + my ds_reads; then barrier
    }

    // ---- epilogue: split-K accumulate. C/D: col=lane&15 (n), row=(lane>>4)*4+e (m) ----
#pragma unroll
    for (int mf = 0; mf < 4; ++mf) {
        const int rg = m0g + wm * 64 + mf * 16 + lhi * 4;
#pragma unroll
        for (int nf = 0; nf < 4; ++nf) {
            const int cg = n0g + wn * 64 + nf * 16 + l15;
#pragma unroll
            for (int e = 0; e < 4; ++e)
                atomicAdd(out + (size_t)(rg + e) * OUT_DIM + cg, acc[mf][nf][e]);
        }
    }
}

// ---------------- fallback (no workspace): round-1 proven kernel ----------------
#define BM 128
#define BN 128
#define FBK 64
#define FKPER  4608
#define FSTEPS 72
__launch_bounds__(256, 2)
__global__ void kan_gemm_ref(const float* __restrict__ x,
                             const float* __restrict__ coeff,
                             const float* __restrict__ scale,
                             float* __restrict__ out) {
    __shared__ unsigned short AsF[BM * 72];
    __shared__ unsigned short BsF[8 * BN * 8];
    const int tid  = threadIdx.x;
    const int lane = tid & 63;
    const int wave = tid >> 6;
    const int wm = wave >> 1, wn = wave & 1;
    const int l15 = lane & 15, lhi = lane >> 4;
    const int bid = blockIdx.x;
    const int nt = bid & 3;
    const int ks = (bid >> 2) & 3;
    const int mt = bid >> 4;
    const int m0g = mt * BM, n0g = nt * BN, kbase = ks * FKPER;
    const int ar = tid >> 1, ah = tid & 1;
    const int abrow = m0g + ar;
    const int bjg = n0g + (tid & 127);
    const float bscale = scale[bjg];
    char* AsB = (char*)AsF;
    char* BsB = (char*)BsF;
    f32x4 acc[4][4] = {};
    for (int step = 0; step < FSTEPS; ++step) {
        const int k0 = kbase + step * FBK;
        {
            char* rb = AsB + ar * 144;
            u32x4 z = {};
            if (ah == 0) {
#pragma unroll
                for (int z4 = 0; z4 < 4; ++z4) *(u32x4*)(rb + z4 * 16) = z;
            } else {
#pragma unroll
                for (int z4 = 4; z4 < 9; ++z4) *(u32x4*)(rb + z4 * 16) = z;
            }
            const int ifirst = k0 / 36;
#pragma unroll
            for (int ii = 0; ii < 2; ++ii) {
                const int cand = ah + ii * 2;
                const int i = ifirst + cand;
                if (cand < 3 && i * 36 < k0 + FBK && i < IN_DIM) {
                    uint2 rec = spline_rec_packed(x[(size_t)abrow * IN_DIM + i]);
                    int s = (int)(rec.y >> 16);
                    const int off = i * 36 + s * 4 - k0;
                    unsigned int w0 = 0x3F80u | (rec.x << 16);
                    unsigned int w1 = (rec.x >> 16) | (rec.y << 16);
                    if (off >= 0 && off <= 62) *(unsigned int*)(rb + off * 2) = w0;
                    const int off2 = off + 2;
                    if (off2 >= 0 && off2 <= 62) *(unsigned int*)(rb + off2 * 2) = w1;
                }
            }
        }
#pragma unroll
        for (int it = 0; it < 4; ++it) {
            const int q  = it * 256 + tid;
            const int c  = q >> 7;
            const int kk = k0 + c * 8;
            f32x4 a = *(const f32x4*)(coeff + (size_t)bjg * KTOT + kk);
            f32x4 b = *(const f32x4*)(coeff + (size_t)bjg * KTOT + kk + 4);
            u32x4 o;
            o.x = f2bf(a.x * bscale) | (f2bf(a.y * bscale) << 16);
            o.y = f2bf(a.z * bscale) | (f2bf(a.w * bscale) << 16);
            o.z = f2bf(b.x * bscale) | (f2bf(b.y * bscale) << 16);
            o.w = f2bf(b.z * bscale) | (f2bf(b.w * bscale) << 16);
            *(u32x4*)(BsB + q * 16) = o;
        }
        __syncthreads();
#pragma unroll
        for (int kh = 0; kh < 2; ++kh) {
            const int kk = kh * 32;
            s16x8 a[4], b[4];
#pragma unroll
            for (int mf = 0; mf < 4; ++mf)
                a[mf] = *(const s16x8*)(AsB + (wm * 64 + mf * 16 + l15) * 144 + (kk + lhi * 8) * 2);
#pragma unroll
            for (int nf = 0; nf < 4; ++nf)
                b[nf] = *(const s16x8*)(BsB + (kh * 4 + lhi) * 2048 + (wn * 64 + nf * 16 + l15) * 16);
#pragma unroll
            for (int mf = 0; mf < 4; ++mf)
#pragma unroll
                for (int nf = 0; nf < 4; ++nf)
                    acc[mf][nf] = __builtin_amdgcn_mfma_f32_16x16x32_bf16(a[mf], b[nf], acc[mf][nf], 0, 0, 0);
        }
        __syncthreads();
    }
#pragma unroll
    for (int mf = 0; mf < 4; ++mf) {
        const int cmBase = m0g + wm * 64 + mf * 16 + lhi * 4;
#pragma unroll
        for (int nf = 0; nf < 4; ++nf) {
            const int cn = n0g + wn * 64 + nf * 16 + l15;
#pragma unroll
            for (int e = 0; e < 4; ++e)
                atomicAdd(out + (size_t)(cmBase + e) * OUT_DIM + cn, acc[mf][nf][e]);
        }
    }
}

extern "C" void kernel_launch(void* const* d_in, const int* in_sizes, int n_in,
                              void* d_out, int out_size, void* d_ws, size_t ws_size,
                              hipStream_t stream) {
    const float* x     = (const float*)d_in[0];
    const float* coeff = (const float*)d_in[1];
    const float* scale = (const float*)d_in[2];
    float* out = (float*)d_out;

    const size_t SZ_CBF = (size_t)OUT_DIM * KTOT * 2;   // 18,874,368
    const size_t SZ_TP  = (size_t)B_DIM * IN_DIM * 8;   // 16,777,216
    const size_t NEED   = SZ_CBF + SZ_TP;               // ~35.7 MB

    hipMemsetAsync(d_out, 0, (size_t)B_DIM * OUT_DIM * sizeof(float), stream);

    if (ws_size >= NEED) {
        unsigned short* cbf2 = (unsigned short*)d_ws;
        uint2*          tp   = (uint2*)((char*)d_ws + SZ_CBF);
        prep_coeff2<<<4608, 256, 0, stream>>>(coeff, scale, (u32x4*)cbf2);
        prep_x_kernel<<<8192, 256, 0, stream>>>(x, tp);
        kan_gemm_db<<<1024, 256, 0, stream>>>(cbf2, tp, out);
    } else {
        kan_gemm_ref<<<512, 256, 0, stream>>>(x, coeff, scale, out);
    }
}